// Round 2
// baseline (116.222 us; speedup 1.0000x reference)
//
#include <hip/hip_runtime.h>

// SimpleGNN: B=4, N=512, D=128, L=2
// Algebraic rewrite: sum over j commutes with the (linear) second layer:
//   msg[b,i,:] = (sum_j adj[b,i,j]*relu(ai'[b,i,:]+aj[b,j,:])) @ w2^T
//              + (sum_j adj[b,i,j]) * b2
// where ai' = h @ wi^T + b1, aj = h @ wj^T.

constexpr int Bc = 4, Nc = 512, Dc = 128, Lc = 2;
constexpr int BN = Bc * Nc; // 2048
constexpr int TI = 4;       // rows per msg block
constexpr int JS = 2;       // j-split factor (partial sums)
constexpr int TN = 4;       // rows per lin block

// --- weight transpose: wiT[l][d][o] = w1[l][o][d], wjT[l][d][o] = w1[l][o][D+d],
//                       w2T[l][d][o] = w2[l][o][d]
__global__ void transpose_w_kernel(const float* __restrict__ w1,
                                   const float* __restrict__ w2,
                                   float* __restrict__ wiT,
                                   float* __restrict__ wjT,
                                   float* __restrict__ w2T) {
    int idx = blockIdx.x * blockDim.x + threadIdx.x;
    if (idx >= Lc * Dc * Dc) return;
    int l = idx / (Dc * Dc);
    int rem = idx - l * Dc * Dc;
    int d = rem / Dc;
    int o = rem - d * Dc;
    wiT[idx] = w1[(l * Dc + o) * (2 * Dc) + d];
    wjT[idx] = w1[(l * Dc + o) * (2 * Dc) + Dc + d];
    w2T[idx] = w2[(l * Dc + o) * Dc + d];
}

// --- first linear: ai'[r][o] = sum_d h[r][d]*wiT[d][o] + b1[o];  aj[r][o] = sum_d h[r][d]*wjT[d][o]
__global__ __launch_bounds__(128) void gnn_lin1(const float* __restrict__ h,
                                                const float* __restrict__ wiT,
                                                const float* __restrict__ wjT,
                                                const float* __restrict__ b1,
                                                float* __restrict__ ai,
                                                float* __restrict__ aj) {
    __shared__ float hs[TN][Dc];
    const int o = threadIdx.x;
    const int r0 = blockIdx.x * TN;
#pragma unroll
    for (int t = 0; t < TN; ++t) hs[t][o] = h[(r0 + t) * Dc + o];
    __syncthreads();
    float acci[TN], accj[TN];
    const float bo = b1[o];
#pragma unroll
    for (int t = 0; t < TN; ++t) { acci[t] = bo; accj[t] = 0.f; }
    for (int d = 0; d < Dc; d += 4) {
        float wi[4], wj[4];
#pragma unroll
        for (int k = 0; k < 4; ++k) {
            wi[k] = wiT[(d + k) * Dc + o];
            wj[k] = wjT[(d + k) * Dc + o];
        }
#pragma unroll
        for (int t = 0; t < TN; ++t) {
            const float4 hv = *reinterpret_cast<const float4*>(&hs[t][d]);
            acci[t] = fmaf(hv.x, wi[0], acci[t]);
            acci[t] = fmaf(hv.y, wi[1], acci[t]);
            acci[t] = fmaf(hv.z, wi[2], acci[t]);
            acci[t] = fmaf(hv.w, wi[3], acci[t]);
            accj[t] = fmaf(hv.x, wj[0], accj[t]);
            accj[t] = fmaf(hv.y, wj[1], accj[t]);
            accj[t] = fmaf(hv.z, wj[2], accj[t]);
            accj[t] = fmaf(hv.w, wj[3], accj[t]);
        }
    }
#pragma unroll
    for (int t = 0; t < TN; ++t) {
        ai[(r0 + t) * Dc + o] = acci[t];
        aj[(r0 + t) * Dc + o] = accj[t];
    }
}

// --- masked-relu reduction over a j-range (partial over js):
//   sp[js][r][d] = sum_{j in range} adj[b,i,j] * relu(ai'[r][d] + aj[b,j,d])
//   arowp[js][r] = sum_{j in range} adj[b,i,j]
// grid = (BN/TI)*JS, 256 threads: tid = half*128 + d; each half does JT/2 j's.
__global__ __launch_bounds__(256) void gnn_msg(const float* __restrict__ ai,
                                               const float* __restrict__ aj,
                                               const float* __restrict__ adj,
                                               float* __restrict__ sp,
                                               float* __restrict__ arowp) {
    constexpr int JT = Nc / JS;  // 256 j's per block
    constexpr int JH = JT / 2;   // 128 per half
    __shared__ float adjs[2][JH][TI];
    __shared__ float accred[TI][128];
    __shared__ float wsum[4][TI];

    const int tid = threadIdx.x;
    const int d = tid & 127;
    const int half = tid >> 7;
    const int js = blockIdx.x & (JS - 1);
    const int rblk = blockIdx.x >> 1;   // JS==2
    const int r0 = rblk * TI;
    const int b = r0 / Nc;
    const int i0 = r0 - b * Nc;
    const int j0 = js * JT + half * JH;

    const float* __restrict__ ajb = aj + b * Nc * Dc;
    const float* __restrict__ adjb = adj + (size_t)b * Nc * Nc;

    float x[TI], acc[TI], ps[TI];
#pragma unroll
    for (int t = 0; t < TI; ++t) {
        x[t] = ai[(r0 + t) * Dc + d];
        acc[t] = 0.f;
    }
    // stage this half's adj columns: JH == 128 == d-range
#pragma unroll
    for (int t = 0; t < TI; ++t) {
        const float v = adjb[(i0 + t) * Nc + j0 + d];
        adjs[half][d][t] = v;
        ps[t] = v;
    }
    __syncthreads();

#pragma unroll 8
    for (int jj = 0; jj < JH; ++jj) {
        const float v = ajb[(j0 + jj) * Dc + d];
        const float4 a4 = *reinterpret_cast<const float4*>(&adjs[half][jj][0]);
        acc[0] = fmaf(a4.x, fmaxf(x[0] + v, 0.f), acc[0]);
        acc[1] = fmaf(a4.y, fmaxf(x[1] + v, 0.f), acc[1]);
        acc[2] = fmaf(a4.z, fmaxf(x[2] + v, 0.f), acc[2]);
        acc[3] = fmaf(a4.w, fmaxf(x[3] + v, 0.f), acc[3]);
    }

    // combine the two j-halves of this block
    if (half == 1) {
#pragma unroll
        for (int t = 0; t < TI; ++t) accred[t][d] = acc[t];
    }
    __syncthreads();
    if (half == 0) {
#pragma unroll
        for (int t = 0; t < TI; ++t)
            sp[((size_t)js * BN + r0 + t) * Dc + d] = acc[t] + accred[t][d];
    }

    // arow partial: wave shfl reduce, then cross-wave via LDS
#pragma unroll
    for (int t = 0; t < TI; ++t) {
#pragma unroll
        for (int off = 32; off >= 1; off >>= 1) ps[t] += __shfl_down(ps[t], off);
    }
    if ((tid & 63) == 0) {
#pragma unroll
        for (int t = 0; t < TI; ++t) wsum[tid >> 6][t] = ps[t];
    }
    __syncthreads();
    if (tid < TI) {
        arowp[(size_t)js * BN + r0 + tid] =
            wsum[0][tid] + wsum[1][tid] + wsum[2][tid] + wsum[3][tid];
    }
}

// --- final second linear + residual (sums JS partials):
__global__ __launch_bounds__(128) void gnn_lin2(const float* __restrict__ hin,
                                                const float* __restrict__ sp,
                                                const float* __restrict__ arowp,
                                                const float* __restrict__ w2T,
                                                const float* __restrict__ b2,
                                                float* __restrict__ hout) {
    __shared__ float ss[TN][Dc];
    const int o = threadIdx.x;
    const int r0 = blockIdx.x * TN;
#pragma unroll
    for (int t = 0; t < TN; ++t)
        ss[t][o] = sp[(size_t)(r0 + t) * Dc + o] + sp[((size_t)BN + r0 + t) * Dc + o];
    __syncthreads();
    float acc[TN];
#pragma unroll
    for (int t = 0; t < TN; ++t) acc[t] = 0.f;
    for (int d = 0; d < Dc; d += 4) {
        float w[4];
#pragma unroll
        for (int k = 0; k < 4; ++k) w[k] = w2T[(d + k) * Dc + o];
#pragma unroll
        for (int t = 0; t < TN; ++t) {
            const float4 sv = *reinterpret_cast<const float4*>(&ss[t][d]);
            acc[t] = fmaf(sv.x, w[0], acc[t]);
            acc[t] = fmaf(sv.y, w[1], acc[t]);
            acc[t] = fmaf(sv.z, w[2], acc[t]);
            acc[t] = fmaf(sv.w, w[3], acc[t]);
        }
    }
    const float b2o = b2[o];
#pragma unroll
    for (int t = 0; t < TN; ++t) {
        const float ar = arowp[r0 + t] + arowp[BN + r0 + t];
        hout[(r0 + t) * Dc + o] = hin[(r0 + t) * Dc + o] + acc[t] + ar * b2o;
    }
}

// --- fused: lin2 of layer l (partials) + residual, then lin1 of layer l+1.
__global__ __launch_bounds__(128) void gnn_lin2lin1(const float* __restrict__ hin,
                                                    const float* __restrict__ sp,
                                                    const float* __restrict__ arowp,
                                                    const float* __restrict__ w2T,
                                                    const float* __restrict__ b2,
                                                    const float* __restrict__ wiT,
                                                    const float* __restrict__ wjT,
                                                    const float* __restrict__ b1,
                                                    float* __restrict__ hout,
                                                    float* __restrict__ ai,
                                                    float* __restrict__ aj) {
    __shared__ float ss[TN][Dc];
    const int o = threadIdx.x;
    const int r0 = blockIdx.x * TN;
#pragma unroll
    for (int t = 0; t < TN; ++t)
        ss[t][o] = sp[(size_t)(r0 + t) * Dc + o] + sp[((size_t)BN + r0 + t) * Dc + o];
    __syncthreads();
    float acc[TN];
#pragma unroll
    for (int t = 0; t < TN; ++t) acc[t] = 0.f;
    for (int d = 0; d < Dc; d += 4) {
        float w[4];
#pragma unroll
        for (int k = 0; k < 4; ++k) w[k] = w2T[(d + k) * Dc + o];
#pragma unroll
        for (int t = 0; t < TN; ++t) {
            const float4 sv = *reinterpret_cast<const float4*>(&ss[t][d]);
            acc[t] = fmaf(sv.x, w[0], acc[t]);
            acc[t] = fmaf(sv.y, w[1], acc[t]);
            acc[t] = fmaf(sv.z, w[2], acc[t]);
            acc[t] = fmaf(sv.w, w[3], acc[t]);
        }
    }
    const float b2o = b2[o];
    float hnew[TN];
#pragma unroll
    for (int t = 0; t < TN; ++t) {
        const float ar = arowp[r0 + t] + arowp[BN + r0 + t];
        hnew[t] = hin[(r0 + t) * Dc + o] + acc[t] + ar * b2o;
        hout[(r0 + t) * Dc + o] = hnew[t];
    }
    // --- lin1 of next layer on hnew ---
    __syncthreads();   // everyone done reading ss
#pragma unroll
    for (int t = 0; t < TN; ++t) ss[t][o] = hnew[t];
    __syncthreads();
    float acci[TN], accj[TN];
    const float bo = b1[o];
#pragma unroll
    for (int t = 0; t < TN; ++t) { acci[t] = bo; accj[t] = 0.f; }
    for (int d = 0; d < Dc; d += 4) {
        float wi[4], wj[4];
#pragma unroll
        for (int k = 0; k < 4; ++k) {
            wi[k] = wiT[(d + k) * Dc + o];
            wj[k] = wjT[(d + k) * Dc + o];
        }
#pragma unroll
        for (int t = 0; t < TN; ++t) {
            const float4 hv = *reinterpret_cast<const float4*>(&ss[t][d]);
            acci[t] = fmaf(hv.x, wi[0], acci[t]);
            acci[t] = fmaf(hv.y, wi[1], acci[t]);
            acci[t] = fmaf(hv.z, wi[2], acci[t]);
            acci[t] = fmaf(hv.w, wi[3], acci[t]);
            accj[t] = fmaf(hv.x, wj[0], accj[t]);
            accj[t] = fmaf(hv.y, wj[1], accj[t]);
            accj[t] = fmaf(hv.z, wj[2], accj[t]);
            accj[t] = fmaf(hv.w, wj[3], accj[t]);
        }
    }
#pragma unroll
    for (int t = 0; t < TN; ++t) {
        ai[(r0 + t) * Dc + o] = acci[t];
        aj[(r0 + t) * Dc + o] = accj[t];
    }
}

extern "C" void kernel_launch(void* const* d_in, const int* in_sizes, int n_in,
                              void* d_out, int out_size, void* d_ws, size_t ws_size,
                              hipStream_t stream) {
    const float* node = (const float*)d_in[0];
    const float* adj  = (const float*)d_in[1];
    const float* w1   = (const float*)d_in[2];
    const float* b1   = (const float*)d_in[3];
    const float* w2   = (const float*)d_in[4];
    const float* b2   = (const float*)d_in[5];
    float* out = (float*)d_out;

    float* ws = (float*)d_ws;
    float* wiT  = ws; ws += Lc * Dc * Dc;
    float* wjT  = ws; ws += Lc * Dc * Dc;
    float* w2T  = ws; ws += Lc * Dc * Dc;
    float* ai   = ws; ws += BN * Dc;
    float* aj   = ws; ws += BN * Dc;
    float* sp   = ws; ws += (size_t)JS * BN * Dc;
    float* arowp= ws; ws += JS * BN;
    float* h1   = ws; ws += BN * Dc;

    transpose_w_kernel<<<(Lc * Dc * Dc + 255) / 256, 256, 0, stream>>>(w1, w2, wiT, wjT, w2T);

    // layer 0
    gnn_lin1<<<BN / TN, 128, 0, stream>>>(node, wiT, wjT, b1, ai, aj);
    gnn_msg<<<(BN / TI) * JS, 256, 0, stream>>>(ai, aj, adj, sp, arowp);
    gnn_lin2lin1<<<BN / TN, 128, 0, stream>>>(node, sp, arowp, w2T, b2,
                                              wiT + Dc * Dc, wjT + Dc * Dc, b1 + Dc,
                                              h1, ai, aj);
    // layer 1
    gnn_msg<<<(BN / TI) * JS, 256, 0, stream>>>(ai, aj, adj, sp, arowp);
    gnn_lin2<<<BN / TN, 128, 0, stream>>>(h1, sp, arowp, w2T + Dc * Dc, b2 + Dc, out);
}

// Round 3
// 67.904 us; speedup vs baseline: 1.7116x; 1.7116x over previous
//
#include <hip/hip_runtime.h>

// SimpleGNN: B=4, N=512, D=128, L=2
// Algebraic rewrite: sum over j commutes with the (linear) second layer:
//   msg[b,i,:] = (sum_j adj[b,i,j]*relu(ai'[b,i,:]+aj[b,j,:])) @ w2^T
//              + (sum_j adj[b,i,j]) * b2
// where ai' = h @ wi^T + b1, aj = h @ wj^T.
// msg kernel: all inner-loop operands come from LDS (double-buffered aj tiles),
// so global-load latency is never on the critical path.

constexpr int Bc = 4, Nc = 512, Dc = 128, Lc = 2;
constexpr int BN = Bc * Nc; // 2048
constexpr int TI = 8;       // i-rows per msg block
constexpr int JS = 4;       // j-split factor (partial sums)
constexpr int JT = Nc / JS; // 128 j's per block
constexpr int JH = JT / 2;  // 64 j's per half
constexpr int JB = 8;       // j's per staged tile (per half)
constexpr int NT = JH / JB; // 8 tiles
constexpr int TN = 4;       // rows per lin block

// --- weight transpose: wiT[l][d][o] = w1[l][o][d], wjT[l][d][o] = w1[l][o][D+d],
//                       w2T[l][d][o] = w2[l][o][d]
__global__ void transpose_w_kernel(const float* __restrict__ w1,
                                   const float* __restrict__ w2,
                                   float* __restrict__ wiT,
                                   float* __restrict__ wjT,
                                   float* __restrict__ w2T) {
    int idx = blockIdx.x * blockDim.x + threadIdx.x;
    if (idx >= Lc * Dc * Dc) return;
    int l = idx / (Dc * Dc);
    int rem = idx - l * Dc * Dc;
    int d = rem / Dc;
    int o = rem - d * Dc;
    wiT[idx] = w1[(l * Dc + o) * (2 * Dc) + d];
    wjT[idx] = w1[(l * Dc + o) * (2 * Dc) + Dc + d];
    w2T[idx] = w2[(l * Dc + o) * Dc + d];
}

// --- first linear
__global__ __launch_bounds__(128) void gnn_lin1(const float* __restrict__ h,
                                                const float* __restrict__ wiT,
                                                const float* __restrict__ wjT,
                                                const float* __restrict__ b1,
                                                float* __restrict__ ai,
                                                float* __restrict__ aj) {
    __shared__ float hs[TN][Dc];
    const int o = threadIdx.x;
    const int r0 = blockIdx.x * TN;
#pragma unroll
    for (int t = 0; t < TN; ++t) hs[t][o] = h[(r0 + t) * Dc + o];
    __syncthreads();
    float acci[TN], accj[TN];
    const float bo = b1[o];
#pragma unroll
    for (int t = 0; t < TN; ++t) { acci[t] = bo; accj[t] = 0.f; }
    for (int d = 0; d < Dc; d += 4) {
        float wi[4], wj[4];
#pragma unroll
        for (int k = 0; k < 4; ++k) {
            wi[k] = wiT[(d + k) * Dc + o];
            wj[k] = wjT[(d + k) * Dc + o];
        }
#pragma unroll
        for (int t = 0; t < TN; ++t) {
            const float4 hv = *reinterpret_cast<const float4*>(&hs[t][d]);
            acci[t] = fmaf(hv.x, wi[0], acci[t]);
            acci[t] = fmaf(hv.y, wi[1], acci[t]);
            acci[t] = fmaf(hv.z, wi[2], acci[t]);
            acci[t] = fmaf(hv.w, wi[3], acci[t]);
            accj[t] = fmaf(hv.x, wj[0], accj[t]);
            accj[t] = fmaf(hv.y, wj[1], accj[t]);
            accj[t] = fmaf(hv.z, wj[2], accj[t]);
            accj[t] = fmaf(hv.w, wj[3], accj[t]);
        }
    }
#pragma unroll
    for (int t = 0; t < TN; ++t) {
        ai[(r0 + t) * Dc + o] = acci[t];
        aj[(r0 + t) * Dc + o] = accj[t];
    }
}

// --- masked-relu reduction over a j-range (partial over js):
//   sp[js][r][d] = sum_{j in range} adj[b,i,j] * relu(ai'[r][d] + aj[b,j,d])
//   arowp[js][r] = sum_{j in range} adj[b,i,j]
// 256 threads: tid = half*128 + d. Each half consumes its own JH j's from
// double-buffered LDS tiles; adj slice staged once, transposed for b128 broadcast.
__global__ __launch_bounds__(256) void gnn_msg(const float* __restrict__ ai,
                                               const float* __restrict__ aj,
                                               const float* __restrict__ adj,
                                               float* __restrict__ sp,
                                               float* __restrict__ arowp) {
    __shared__ float ajs[2][2][JB][Dc];  // [half][buf][jj][d]  32 KB
    __shared__ float adjsT[JT][TI];      // [j][t] 4 KB; reused as accred after loop

    const int tid = threadIdx.x;
    const int d = tid & 127;
    const int half = tid >> 7;
    const int js = blockIdx.x & (JS - 1);
    const int rblk = blockIdx.x >> 2;    // JS==4
    const int r0 = rblk * TI;
    const int b = r0 / Nc;
    const int i0 = r0 - b * Nc;
    const int j0 = js * JT;
    const int j0h = j0 + half * JH;
    const float* __restrict__ ajb = aj + b * Nc * Dc;
    const float* __restrict__ adjb = adj + (size_t)b * Nc * Nc;

    // ---- stage adj slice (transposed) + arow partials
    {
        const int rr = tid >> 5;            // 0..7
        const int c4 = (tid & 31) * 4;      // 0..124
        const float4 av = *reinterpret_cast<const float4*>(&adjb[(i0 + rr) * Nc + j0 + c4]);
        adjsT[c4 + 0][rr] = av.x;
        adjsT[c4 + 1][rr] = av.y;
        adjsT[c4 + 2][rr] = av.z;
        adjsT[c4 + 3][rr] = av.w;
        float ps = av.x + av.y + av.z + av.w;
#pragma unroll
        for (int m = 16; m >= 1; m >>= 1) ps += __shfl_xor(ps, m);
        if ((tid & 31) == 0) arowp[js * BN + r0 + rr] = ps;
    }

    float x[TI], acc[TI];
#pragma unroll
    for (int r = 0; r < TI; ++r) {
        x[r] = ai[(r0 + r) * Dc + d];
        acc[r] = 0.f;
    }

    // ---- aj tile prefetch: per half, JB*Dc = 1024 floats = 128 thr x 2 float4
    const int jjA = d >> 5;        // 0..3
    const int jjB = jjA + 4;       // 4..7
    const int d4 = (d & 31) * 4;
    float4 pfA, pfB;

#define LOADTILE(tt)                                                             \
    {                                                                            \
        const float* base_ = ajb + (j0h + (tt) * JB) * Dc;                       \
        pfA = *reinterpret_cast<const float4*>(&base_[jjA * Dc + d4]);           \
        pfB = *reinterpret_cast<const float4*>(&base_[jjB * Dc + d4]);           \
    }
#define STORETILE(bf)                                                            \
    {                                                                            \
        *reinterpret_cast<float4*>(&ajs[half][bf][jjA][d4]) = pfA;               \
        *reinterpret_cast<float4*>(&ajs[half][bf][jjB][d4]) = pfB;               \
    }

    LOADTILE(0);
    STORETILE(0);
    LOADTILE(1);
    __syncthreads();

    for (int tt = 0; tt < NT; ++tt) {
        const int buf = tt & 1;
        if (tt + 1 < NT) {
            STORETILE(buf ^ 1);                 // write tile tt+1 (regs already loaded)
            if (tt + 2 < NT) LOADTILE(tt + 2);  // issue loads; in flight during consume
        }
        const int jg0 = half * JH + tt * JB;
#pragma unroll
        for (int jj = 0; jj < JB; ++jj) {
            const float v = ajs[half][buf][jj][d];
            const float4 a0 = *reinterpret_cast<const float4*>(&adjsT[jg0 + jj][0]);
            const float4 a1 = *reinterpret_cast<const float4*>(&adjsT[jg0 + jj][4]);
            acc[0] = fmaf(a0.x, fmaxf(x[0] + v, 0.f), acc[0]);
            acc[1] = fmaf(a0.y, fmaxf(x[1] + v, 0.f), acc[1]);
            acc[2] = fmaf(a0.z, fmaxf(x[2] + v, 0.f), acc[2]);
            acc[3] = fmaf(a0.w, fmaxf(x[3] + v, 0.f), acc[3]);
            acc[4] = fmaf(a1.x, fmaxf(x[4] + v, 0.f), acc[4]);
            acc[5] = fmaf(a1.y, fmaxf(x[5] + v, 0.f), acc[5]);
            acc[6] = fmaf(a1.z, fmaxf(x[6] + v, 0.f), acc[6]);
            acc[7] = fmaf(a1.w, fmaxf(x[7] + v, 0.f), acc[7]);
        }
        __syncthreads();
    }
#undef LOADTILE
#undef STORETILE

    // ---- combine halves (reuse adjsT storage as accred[TI][Dc] = 1024 floats)
    float* accred = &adjsT[0][0];
    if (half == 1) {
#pragma unroll
        for (int r = 0; r < TI; ++r) accred[r * Dc + d] = acc[r];
    }
    __syncthreads();
    if (half == 0) {
#pragma unroll
        for (int r = 0; r < TI; ++r)
            sp[((size_t)js * BN + r0 + r) * Dc + d] = acc[r] + accred[r * Dc + d];
    }
}

// --- final second linear + residual (sums JS partials):
__global__ __launch_bounds__(128) void gnn_lin2(const float* __restrict__ hin,
                                                const float* __restrict__ sp,
                                                const float* __restrict__ arowp,
                                                const float* __restrict__ w2T,
                                                const float* __restrict__ b2,
                                                float* __restrict__ hout) {
    __shared__ float ss[TN][Dc];
    const int o = threadIdx.x;
    const int r0 = blockIdx.x * TN;
#pragma unroll
    for (int t = 0; t < TN; ++t) {
        float v = 0.f;
#pragma unroll
        for (int js = 0; js < JS; ++js) v += sp[((size_t)js * BN + r0 + t) * Dc + o];
        ss[t][o] = v;
    }
    __syncthreads();
    float acc[TN];
#pragma unroll
    for (int t = 0; t < TN; ++t) acc[t] = 0.f;
    for (int d = 0; d < Dc; d += 4) {
        float w[4];
#pragma unroll
        for (int k = 0; k < 4; ++k) w[k] = w2T[(d + k) * Dc + o];
#pragma unroll
        for (int t = 0; t < TN; ++t) {
            const float4 sv = *reinterpret_cast<const float4*>(&ss[t][d]);
            acc[t] = fmaf(sv.x, w[0], acc[t]);
            acc[t] = fmaf(sv.y, w[1], acc[t]);
            acc[t] = fmaf(sv.z, w[2], acc[t]);
            acc[t] = fmaf(sv.w, w[3], acc[t]);
        }
    }
    const float b2o = b2[o];
#pragma unroll
    for (int t = 0; t < TN; ++t) {
        float ar = 0.f;
#pragma unroll
        for (int js = 0; js < JS; ++js) ar += arowp[js * BN + r0 + t];
        hout[(r0 + t) * Dc + o] = hin[(r0 + t) * Dc + o] + acc[t] + ar * b2o;
    }
}

// --- fused: lin2 of layer l (partials) + residual, then lin1 of layer l+1.
__global__ __launch_bounds__(128) void gnn_lin2lin1(const float* __restrict__ hin,
                                                    const float* __restrict__ sp,
                                                    const float* __restrict__ arowp,
                                                    const float* __restrict__ w2T,
                                                    const float* __restrict__ b2,
                                                    const float* __restrict__ wiT,
                                                    const float* __restrict__ wjT,
                                                    const float* __restrict__ b1,
                                                    float* __restrict__ hout,
                                                    float* __restrict__ ai,
                                                    float* __restrict__ aj) {
    __shared__ float ss[TN][Dc];
    const int o = threadIdx.x;
    const int r0 = blockIdx.x * TN;
#pragma unroll
    for (int t = 0; t < TN; ++t) {
        float v = 0.f;
#pragma unroll
        for (int js = 0; js < JS; ++js) v += sp[((size_t)js * BN + r0 + t) * Dc + o];
        ss[t][o] = v;
    }
    __syncthreads();
    float acc[TN];
#pragma unroll
    for (int t = 0; t < TN; ++t) acc[t] = 0.f;
    for (int d = 0; d < Dc; d += 4) {
        float w[4];
#pragma unroll
        for (int k = 0; k < 4; ++k) w[k] = w2T[(d + k) * Dc + o];
#pragma unroll
        for (int t = 0; t < TN; ++t) {
            const float4 sv = *reinterpret_cast<const float4*>(&ss[t][d]);
            acc[t] = fmaf(sv.x, w[0], acc[t]);
            acc[t] = fmaf(sv.y, w[1], acc[t]);
            acc[t] = fmaf(sv.z, w[2], acc[t]);
            acc[t] = fmaf(sv.w, w[3], acc[t]);
        }
    }
    const float b2o = b2[o];
    float hnew[TN];
#pragma unroll
    for (int t = 0; t < TN; ++t) {
        float ar = 0.f;
#pragma unroll
        for (int js = 0; js < JS; ++js) ar += arowp[js * BN + r0 + t];
        hnew[t] = hin[(r0 + t) * Dc + o] + acc[t] + ar * b2o;
        hout[(r0 + t) * Dc + o] = hnew[t];
    }
    __syncthreads();
#pragma unroll
    for (int t = 0; t < TN; ++t) ss[t][o] = hnew[t];
    __syncthreads();
    float acci[TN], accj[TN];
    const float bo = b1[o];
#pragma unroll
    for (int t = 0; t < TN; ++t) { acci[t] = bo; accj[t] = 0.f; }
    for (int d = 0; d < Dc; d += 4) {
        float wi[4], wj[4];
#pragma unroll
        for (int k = 0; k < 4; ++k) {
            wi[k] = wiT[(d + k) * Dc + o];
            wj[k] = wjT[(d + k) * Dc + o];
        }
#pragma unroll
        for (int t = 0; t < TN; ++t) {
            const float4 hv = *reinterpret_cast<const float4*>(&ss[t][d]);
            acci[t] = fmaf(hv.x, wi[0], acci[t]);
            acci[t] = fmaf(hv.y, wi[1], acci[t]);
            acci[t] = fmaf(hv.z, wi[2], acci[t]);
            acci[t] = fmaf(hv.w, wi[3], acci[t]);
            accj[t] = fmaf(hv.x, wj[0], accj[t]);
            accj[t] = fmaf(hv.y, wj[1], accj[t]);
            accj[t] = fmaf(hv.z, wj[2], accj[t]);
            accj[t] = fmaf(hv.w, wj[3], accj[t]);
        }
    }
#pragma unroll
    for (int t = 0; t < TN; ++t) {
        ai[(r0 + t) * Dc + o] = acci[t];
        aj[(r0 + t) * Dc + o] = accj[t];
    }
}

extern "C" void kernel_launch(void* const* d_in, const int* in_sizes, int n_in,
                              void* d_out, int out_size, void* d_ws, size_t ws_size,
                              hipStream_t stream) {
    const float* node = (const float*)d_in[0];
    const float* adj  = (const float*)d_in[1];
    const float* w1   = (const float*)d_in[2];
    const float* b1   = (const float*)d_in[3];
    const float* w2   = (const float*)d_in[4];
    const float* b2   = (const float*)d_in[5];
    float* out = (float*)d_out;

    float* ws = (float*)d_ws;
    float* wiT  = ws; ws += Lc * Dc * Dc;
    float* wjT  = ws; ws += Lc * Dc * Dc;
    float* w2T  = ws; ws += Lc * Dc * Dc;
    float* ai   = ws; ws += BN * Dc;
    float* aj   = ws; ws += BN * Dc;
    float* sp   = ws; ws += (size_t)JS * BN * Dc;
    float* arowp= ws; ws += JS * BN;
    float* h1   = ws; ws += BN * Dc;

    transpose_w_kernel<<<(Lc * Dc * Dc + 255) / 256, 256, 0, stream>>>(w1, w2, wiT, wjT, w2T);

    // layer 0
    gnn_lin1<<<BN / TN, 128, 0, stream>>>(node, wiT, wjT, b1, ai, aj);
    gnn_msg<<<(BN / TI) * JS, 256, 0, stream>>>(ai, aj, adj, sp, arowp);
    gnn_lin2lin1<<<BN / TN, 128, 0, stream>>>(node, sp, arowp, w2T, b2,
                                              wiT + Dc * Dc, wjT + Dc * Dc, b1 + Dc,
                                              h1, ai, aj);
    // layer 1
    gnn_msg<<<(BN / TI) * JS, 256, 0, stream>>>(ai, aj, adj, sp, arowp);
    gnn_lin2<<<BN / TN, 128, 0, stream>>>(h1, sp, arowp, w2T + Dc * Dc, b2 + Dc, out);
}